// Round 7
// baseline (308.614 us; speedup 1.0000x reference)
//
#include <hip/hip_runtime.h>
#include <hip/hip_bf16.h>

// ---------------------------------------------------------------------------
// GCN (3x GCNConv) + dense head, bf16 MFMA.
// Round 7: let the compiler software-pipeline ds_read<->MFMA (remove the
// full lgkmcnt(0) drain before MFMA; fine-grained waits are auto-inserted),
// move STAGE after the compute barrier, keep counted vmcnt(8). Hoisted
// staging address arithmetic.
// ---------------------------------------------------------------------------

typedef __attribute__((ext_vector_type(8))) short bf16x8;
typedef __attribute__((ext_vector_type(8))) unsigned short u16x8;
typedef __attribute__((ext_vector_type(4))) float f32x4;
typedef unsigned short u16;

#define MPAD 20096   // 20000 padded to multiple of 128

__device__ inline u16 f2b(float f) {
  union { float f; unsigned int u; } x; x.f = f;
  unsigned int r = x.u + 0x7FFFu + ((x.u >> 16) & 1u);   // RNE
  return (u16)(r >> 16);
}
__device__ inline float b2f(u16 u) {
  union { unsigned int u; float f; } x; x.u = ((unsigned int)u) << 16; return x.f;
}

// ----------------------- conversion kernels --------------------------------

__global__ __launch_bounds__(256) void cvt_x(
    const float* __restrict__ in, u16* __restrict__ out, int M, int K) {
  int idx = (blockIdx.x * 256 + threadIdx.x) * 4;
  if (idx >= M * K) return;
  float4 v = *reinterpret_cast<const float4*>(&in[idx]);
  ushort4 o;
  o.x = f2b(v.x); o.y = f2b(v.y); o.z = f2b(v.z); o.w = f2b(v.w);
  *reinterpret_cast<ushort4*>(&out[idx]) = o;
}

// W [K x N] fp32 -> WT [NPAD x KPAD] bf16, zero-filled outside KxN.
__global__ __launch_bounds__(256) void cvt_wT_tile(
    const float* __restrict__ W, u16* __restrict__ WT,
    int K, int N, int KPAD, int NPAD) {
  __shared__ float tile[32][33];
  const int kb = blockIdx.y * 32, nb = blockIdx.x * 32;
  const int tx = threadIdx.x & 31, ty = threadIdx.x >> 5;
  #pragma unroll
  for (int i = 0; i < 4; ++i) {
    int k = kb + ty + i * 8, n = nb + tx;
    tile[ty + i * 8][tx] = (k < K && n < N) ? W[(size_t)k * N + n] : 0.f;
  }
  __syncthreads();
  #pragma unroll
  for (int i = 0; i < 4; ++i) {
    int n = nb + ty + i * 8, k = kb + tx;
    WT[(size_t)n * KPAD + k] = f2b(tile[tx][ty + i * 8]);
  }
}

__global__ __launch_bounds__(256) void pad_bias(
    const float* __restrict__ b, float* __restrict__ bp, int n, int npad) {
  int i = blockIdx.x * 256 + threadIdx.x;
  if (i < npad) bp[i] = (i < n) ? b[i] : 0.f;
}

// ----------------------- CSR build -----------------------------------------

__global__ __launch_bounds__(256) void count_deg(
    const int* __restrict__ dst, int* __restrict__ cnt, int E) {
  int e = blockIdx.x * 256 + threadIdx.x;
  if (e < E) atomicAdd(&cnt[dst[e]], 1);
}

// single-block exclusive scan, wave-shuffle based. 1024 threads = 16 waves.
__global__ __launch_bounds__(1024) void exscan_kernel(
    const int* __restrict__ in, int* __restrict__ out, int n) {
  __shared__ int wsum[16];
  __shared__ int carry_s;
  if (threadIdx.x == 0) carry_s = 0;
  __syncthreads();
  const int lane = threadIdx.x & 63, wv = threadIdx.x >> 6;
  for (int base = 0; base < n; base += 1024) {
    int i = base + threadIdx.x;
    int v = (i < n) ? in[i] : 0;
    int s = v;
    #pragma unroll
    for (int off = 1; off < 64; off <<= 1) {
      int t = __shfl_up(s, off, 64);
      if (lane >= off) s += t;
    }
    if (lane == 63) wsum[wv] = s;
    __syncthreads();
    if (wv == 0 && lane < 16) {
      int t = wsum[lane];
      #pragma unroll
      for (int off = 1; off < 16; off <<= 1) {
        int u = __shfl_up(t, off, 64);
        if (lane >= off) t += u;
      }
      wsum[lane] = t;
    }
    __syncthreads();
    int waveoff = (wv == 0) ? 0 : wsum[wv - 1];
    int res = carry_s + waveoff + s - v;
    if (i < n) out[i] = res;
    __syncthreads();
    if (threadIdx.x == 0) carry_s += wsum[15];
    __syncthreads();
  }
  if (threadIdx.x == 0) out[n] = carry_s;
}

__global__ __launch_bounds__(256) void scatter_csr(
    const int* __restrict__ dst, const int* __restrict__ src,
    const float* __restrict__ ew, const int* __restrict__ row_ptr,
    int* __restrict__ cnt, int* __restrict__ csr_src,
    float* __restrict__ csr_w, int E) {
  int e = blockIdx.x * 256 + threadIdx.x;
  if (e >= E) return;
  int d = dst[e];
  int pos = row_ptr[d] + atomicAdd(&cnt[d], 1);
  csr_src[pos] = src[e];
  csr_w[pos] = ew[e];
}

// ----------------------- bf16 MFMA GEMM, counted-vmcnt 2-phase --------------
// C[M x Nn] = A[M x K] @ B, BT[Nn x K] given (bf16 row-major).
// M,Nn multiples of 128; K multiple of 64 (nk >= 2).
// Loop: {ds_reads + MFMA compiler-interleaved} -> barrier -> STAGE(kt+2)
// -> vmcnt(8) -> barrier.  Loads stay in flight across barriers.
template <int ACT, bool BIAS, bool OUT_BF16>
__global__ __launch_bounds__(256) void gemm_mfma_db(
    const u16* __restrict__ A, const u16* __restrict__ BT,
    const float* __restrict__ bias, void* __restrict__ C,
    int M, int K, int Nn) {
  __shared__ __align__(16) u16 As[2][128 * 64];
  __shared__ __align__(16) u16 Bs[2][128 * 64];
  const int tid = threadIdx.x;
  const int lane = tid & 63;
  const int wave = tid >> 6;
  const int lo = lane & 15, hi = lane >> 4;
  const int wr = wave >> 1, wc = wave & 1;

  // bijective XCD swizzle (m204)
  const int gx = gridDim.x;
  const int nwg = gx * gridDim.y;
  const int wg = blockIdx.y * gx + blockIdx.x;
  const int q = nwg >> 3, r = nwg & 7;
  const int xcd = wg & 7, sidx = wg >> 3;
  const int swz = (xcd < r ? xcd * (q + 1) : r * (q + 1) + (xcd - r) * q) + sidx;
  const int row0 = (swz / gx) * 128;
  const int col0 = (swz % gx) * 128;

  // staging geometry: thread covers 4 chunks of 16B; pre-swizzled source.
  // hoisted base pointers; per-tile offset is ko = kt*64 elements.
  const u16* pa[4];
  const u16* pb[4];
  int so[4];
  #pragma unroll
  for (int i = 0; i < 4; ++i) {
    int o = i * 4096 + tid * 16;
    int rr = o >> 7;
    int ke = ((o & 127) >> 1) ^ ((rr & 7) << 3);
    pa[i] = &A[(size_t)(row0 + rr) * K + ke];
    pb[i] = &BT[(size_t)(col0 + rr) * K + ke];
    so[i] = o >> 1;   // LDS element offset
  }

  const int nk = K >> 6;
  f32x4 acc[4][4] = {};

  auto STAGE = [&](int buf, int kt) {
    const int ko = kt << 6;
    #pragma unroll
    for (int i = 0; i < 4; ++i) {
      __builtin_amdgcn_global_load_lds(
          (const __attribute__((address_space(1))) void*)(pa[i] + ko),
          (__attribute__((address_space(3))) void*)&As[buf][so[i]], 16, 0, 0);
      __builtin_amdgcn_global_load_lds(
          (const __attribute__((address_space(1))) void*)(pb[i] + ko),
          (__attribute__((address_space(3))) void*)&Bs[buf][so[i]], 16, 0, 0);
    }
  };

  STAGE(0, 0);
  STAGE(1, 1);
  asm volatile("s_waitcnt vmcnt(8)" ::: "memory");   // buf0's 8 landed
  __builtin_amdgcn_s_barrier();

  for (int kt = 0; kt < nk; ++kt) {
    const int cur = kt & 1;
    // issue fragment reads; compiler interleaves fine-grained lgkmcnt with MFMA
    bf16x8 af[2][4], bfr[2][4];
    #pragma unroll
    for (int ks = 0; ks < 2; ++ks) {
      #pragma unroll
      for (int m = 0; m < 4; ++m) {
        int row = wr * 64 + m * 16 + lo;
        int idx = (row * 64 + ks * 32 + hi * 8) ^ ((row & 7) << 3);
        af[ks][m] = *reinterpret_cast<const bf16x8*>(&As[cur][idx]);
      }
      #pragma unroll
      for (int n = 0; n < 4; ++n) {
        int col = wc * 64 + n * 16 + lo;
        int idx = (col * 64 + ks * 32 + hi * 8) ^ ((col & 7) << 3);
        bfr[ks][n] = *reinterpret_cast<const bf16x8*>(&Bs[cur][idx]);
      }
    }
    __builtin_amdgcn_s_setprio(1);
    #pragma unroll
    for (int ks = 0; ks < 2; ++ks)
      #pragma unroll
      for (int m = 0; m < 4; ++m)
        #pragma unroll
        for (int n = 0; n < 4; ++n)
          acc[m][n] = __builtin_amdgcn_mfma_f32_16x16x32_bf16(
              af[ks][m], bfr[ks][n], acc[m][n], 0, 0, 0);
    __builtin_amdgcn_s_setprio(0);
    // all reads were consumed by MFMAs above; this wait is free but guarantees
    // no read is still in flight when other waves pass the barrier and STAGE.
    asm volatile("s_waitcnt lgkmcnt(0)" ::: "memory");
    __builtin_amdgcn_s_barrier();
    if (kt + 2 < nk) {
      STAGE(cur, kt + 2);                               // refill cur (async)
      asm volatile("s_waitcnt vmcnt(8)" ::: "memory");  // next buf landed
    } else if (kt + 1 < nk) {
      asm volatile("s_waitcnt vmcnt(0)" ::: "memory");  // last prefetch landed
    }
    __builtin_amdgcn_s_barrier();
  }

  float bv[4];
  if (BIAS) {
    #pragma unroll
    for (int n = 0; n < 4; ++n) bv[n] = bias[col0 + wc * 64 + n * 16 + lo];
  }

  u16* Cb = (u16*)C;
  float* Cf = (float*)C;
  #pragma unroll
  for (int m = 0; m < 4; ++m) {
    int rbase = row0 + wr * 64 + m * 16 + hi * 4;
    #pragma unroll
    for (int n = 0; n < 4; ++n) {
      int c = col0 + wc * 64 + n * 16 + lo;
      #pragma unroll
      for (int i = 0; i < 4; ++i) {
        float v = acc[m][n][i];
        if (BIAS) v += bv[n];
        if (ACT == 1) v = tanhf(v);
        else if (ACT == 2) v = fmaxf(v, 0.f);
        size_t off2 = (size_t)(rbase + i) * Nn + c;
        if (OUT_BF16) Cb[off2] = f2b(v);
        else Cf[off2] = v;
      }
    }
  }
}

// ----------------------- spmm: wave per node, F=512 -------------------------
template <int ACT, bool BIAS, bool OUT_BF16>
__global__ __launch_bounds__(256) void spmm_wave512(
    const int* __restrict__ row_ptr, const int* __restrict__ csr_src,
    const float* __restrict__ csr_w, const u16* __restrict__ H,
    const float* __restrict__ bias, void* __restrict__ out, int N) {
  __shared__ int s_src[4][64];
  __shared__ float s_w[4][64];
  const int wv = threadIdx.x >> 6;
  const int lane = threadIdx.x & 63;
  const int node = blockIdx.x * 4 + wv;
  if (node >= N) return;
  const int c = lane * 8;
  const int beg = row_ptr[node], end = row_ptr[node + 1];

  float a[8] = {};
  for (int p = beg; p < end; p += 64) {
    int cnt = end - p;
    if (cnt > 64) cnt = 64;
    if (lane < cnt) {
      s_src[wv][lane] = csr_src[p + lane];
      s_w[wv][lane] = csr_w[p + lane];
    }
    asm volatile("s_waitcnt lgkmcnt(0)" ::: "memory");
    int j = 0;
    for (; j + 3 < cnt; j += 4) {
      int s0 = s_src[wv][j], s1 = s_src[wv][j + 1];
      int s2 = s_src[wv][j + 2], s3 = s_src[wv][j + 3];
      float w0 = s_w[wv][j], w1 = s_w[wv][j + 1];
      float w2 = s_w[wv][j + 2], w3 = s_w[wv][j + 3];
      u16x8 h0 = *reinterpret_cast<const u16x8*>(&H[(size_t)s0 * 512 + c]);
      u16x8 h1 = *reinterpret_cast<const u16x8*>(&H[(size_t)s1 * 512 + c]);
      u16x8 h2 = *reinterpret_cast<const u16x8*>(&H[(size_t)s2 * 512 + c]);
      u16x8 h3 = *reinterpret_cast<const u16x8*>(&H[(size_t)s3 * 512 + c]);
      #pragma unroll
      for (int k = 0; k < 8; ++k)
        a[k] += w0 * b2f(h0[k]) + w1 * b2f(h1[k]) +
                w2 * b2f(h2[k]) + w3 * b2f(h3[k]);
    }
    for (; j < cnt; ++j) {
      int s = s_src[wv][j];
      float wt = s_w[wv][j];
      u16x8 hv = *reinterpret_cast<const u16x8*>(&H[(size_t)s * 512 + c]);
      #pragma unroll
      for (int k = 0; k < 8; ++k) a[k] += wt * b2f(hv[k]);
    }
    asm volatile("s_waitcnt lgkmcnt(0)" ::: "memory");
  }
  if (BIAS) {
    #pragma unroll
    for (int k = 0; k < 8; ++k) a[k] += bias[c + k];
  }
  if (ACT == 1) {
    #pragma unroll
    for (int k = 0; k < 8; ++k) a[k] = tanhf(a[k]);
  }
  if (OUT_BF16) {
    u16x8 o;
    #pragma unroll
    for (int k = 0; k < 8; ++k) o[k] = f2b(a[k]);
    *reinterpret_cast<u16x8*>(&((u16*)out)[(size_t)node * 512 + c]) = o;
  } else {
    float* op = &((float*)out)[(size_t)node * 512 + c];
    #pragma unroll
    for (int k = 0; k < 8; ++k) op[k] = a[k];
  }
}

// ----------------------- spmm: small F (128) --------------------------------
template <int F, int ACT, bool BIAS, bool OUT_BF16>
__global__ __launch_bounds__(256) void spmm_small(
    const int* __restrict__ row_ptr, const int* __restrict__ csr_src,
    const float* __restrict__ csr_w, const u16* __restrict__ H,
    const float* __restrict__ bias, void* __restrict__ out, int N) {
  constexpr int TPN = F / 8;
  constexpr int NPB = 256 / TPN;
  int sub = threadIdx.x / TPN;
  int ln = threadIdx.x - sub * TPN;
  int node = blockIdx.x * NPB + sub;
  if (node >= N) return;
  int c = ln * 8;
  int beg = row_ptr[node], end = row_ptr[node + 1];
  float a[8] = {};
  for (int p = beg; p < end; ++p) {
    int s = csr_src[p];
    float wt = csr_w[p];
    u16x8 hv = *reinterpret_cast<const u16x8*>(&H[(size_t)s * F + c]);
    #pragma unroll
    for (int k = 0; k < 8; ++k) a[k] += wt * b2f(hv[k]);
  }
  if (BIAS) {
    #pragma unroll
    for (int k = 0; k < 8; ++k) a[k] += bias[c + k];
  }
  if (ACT == 1) {
    #pragma unroll
    for (int k = 0; k < 8; ++k) a[k] = tanhf(a[k]);
  }
  if (OUT_BF16) {
    u16x8 o;
    #pragma unroll
    for (int k = 0; k < 8; ++k) o[k] = f2b(a[k]);
    *reinterpret_cast<u16x8*>(&((u16*)out)[(size_t)node * F + c]) = o;
  } else {
    float* op = &((float*)out)[(size_t)node * F + c];
    #pragma unroll
    for (int k = 0; k < 8; ++k) op[k] = a[k];
  }
}

// out[r] = dot(D2row(bf16)[:48], W[:48]) + b[0]
__global__ __launch_bounds__(256) void last_layer_bf16(
    const u16* __restrict__ D2v, const float* __restrict__ W,
    const float* __restrict__ b, float* __restrict__ out,
    int M, int K, int ld) {
  int rr = blockIdx.x * 256 + threadIdx.x;
  if (rr >= M) return;
  float s = b[0];
  const u16* row = &D2v[(size_t)rr * ld];
  #pragma unroll 8
  for (int k = 0; k < 48; ++k) s += b2f(row[k]) * W[k];
  out[rr] = s;
}

// ---------------------------------------------------------------------------

extern "C" void kernel_launch(void* const* d_in, const int* in_sizes, int n_in,
                              void* d_out, int out_size, void* d_ws, size_t ws_size,
                              hipStream_t stream) {
  const int N = 20000, E = 320000;
  const int F_IN = 512, H1 = 1024, H2 = 512, F_OUT = 128;
  const int D1 = 152, D2 = 48;
  const int D1P = 256, D2P = 128;

  const float* x    = (const float*)d_in[0];
  const int*   src  = (const int*)d_in[1];
  const int*   dst  = (const int*)d_in[2];
  const float* ew   = (const float*)d_in[3];
  const float* W1   = (const float*)d_in[4];
  const float* b1   = (const float*)d_in[5];
  const float* W2   = (const float*)d_in[6];
  const float* b2   = (const float*)d_in[7];
  const float* W3   = (const float*)d_in[8];
  const float* b3   = (const float*)d_in[9];
  const float* Wd1  = (const float*)d_in[10];
  const float* bd1  = (const float*)d_in[11];
  const float* Wd2  = (const float*)d_in[12];
  const float* bd2  = (const float*)d_in[13];
  const float* Wd3  = (const float*)d_in[14];
  const float* bd3  = (const float*)d_in[15];
  float* out = (float*)d_out;

  size_t off = 0;
  auto alloc = [&](size_t bytes) {
    void* p = (char*)d_ws + off;
    off += (bytes + 255) & ~(size_t)255;
    return p;
  };
  u16* xb   = (u16*)alloc((size_t)MPAD * F_IN * 2);    // x bf16; later t2
  u16* ax   = (u16*)alloc((size_t)MPAD * F_IN * 2);    // A@x;   later h2
  u16* h1   = (u16*)alloc((size_t)MPAD * H1 * 2);      // h1 (also t3..d2 region)
  u16* w1t  = (u16*)alloc((size_t)H1 * F_IN * 2);
  u16* w2t  = (u16*)alloc((size_t)H2 * H1 * 2);
  u16* w3t  = (u16*)alloc((size_t)F_OUT * H2 * 2);
  u16* wd1t = (u16*)alloc((size_t)D1P * F_OUT * 2);
  u16* wd2t = (u16*)alloc((size_t)D2P * D1P * 2);
  float* bd1p = (float*)alloc((size_t)D1P * 4);
  float* bd2p = (float*)alloc((size_t)D2P * 4);
  int* row_ptr = (int*)alloc((size_t)(N + 1) * 4);
  int* cnt     = (int*)alloc((size_t)N * 4);
  int* csr_src = (int*)alloc((size_t)E * 4);
  float* csr_w = (float*)alloc((size_t)E * 4);

  u16* t2 = xb;
  u16* h2 = ax;
  u16* t3 = h1;
  u16* gb = t3 + (size_t)MPAD * F_OUT;
  u16* d1 = gb + (size_t)MPAD * F_OUT;
  u16* d2 = d1 + (size_t)MPAD * D1P;

  auto cdiv = [](int a, int b) { return (a + b - 1) / b; };

  // ---- conversions ----
  cvt_x<<<cdiv(N * F_IN / 4, 256), 256, 0, stream>>>(x, xb, N, F_IN);
  cvt_wT_tile<<<dim3(H1 / 32, F_IN / 32), 256, 0, stream>>>(W1, w1t, F_IN, H1, F_IN, H1);
  cvt_wT_tile<<<dim3(H2 / 32, H1 / 32), 256, 0, stream>>>(W2, w2t, H1, H2, H1, H2);
  cvt_wT_tile<<<dim3(F_OUT / 32, H2 / 32), 256, 0, stream>>>(W3, w3t, H2, F_OUT, H2, F_OUT);
  cvt_wT_tile<<<dim3(D1P / 32, F_OUT / 32), 256, 0, stream>>>(Wd1, wd1t, F_OUT, D1, F_OUT, D1P);
  cvt_wT_tile<<<dim3(D2P / 32, D1P / 32), 256, 0, stream>>>(Wd2, wd2t, D1, D2, D1P, D2P);
  pad_bias<<<1, 256, 0, stream>>>(bd1, bd1p, D1, D1P);
  pad_bias<<<1, 256, 0, stream>>>(bd2, bd2p, D2, D2P);

  // ---- CSR build ----
  hipMemsetAsync(cnt, 0, (size_t)N * 4, stream);
  count_deg<<<cdiv(E, 256), 256, 0, stream>>>(dst, cnt, E);
  exscan_kernel<<<1, 1024, 0, stream>>>(cnt, row_ptr, N);
  hipMemsetAsync(cnt, 0, (size_t)N * 4, stream);
  scatter_csr<<<cdiv(E, 256), 256, 0, stream>>>(dst, src, ew, row_ptr, cnt,
                                                csr_src, csr_w, E);

  // ---- layer 1 (reordered): ax = A@x ; h1 = tanh(ax@W1 + b1) ----
  spmm_wave512<0, false, true><<<cdiv(N, 4), 256, 0, stream>>>(
      row_ptr, csr_src, csr_w, xb, nullptr, ax, N);
  gemm_mfma_db<1, true, true><<<dim3(H1 / 128, MPAD / 128), 256, 0, stream>>>(
      ax, w1t, b1, h1, MPAD, F_IN, H1);

  // ---- layer 2: t2 = h1@W2 ; h2 = tanh(A@t2 + b2) ----
  gemm_mfma_db<0, false, true><<<dim3(H2 / 128, MPAD / 128), 256, 0, stream>>>(
      h1, w2t, nullptr, t2, MPAD, H1, H2);
  spmm_wave512<1, true, true><<<cdiv(N, 4), 256, 0, stream>>>(
      row_ptr, csr_src, csr_w, t2, b2, h2, N);

  // ---- layer 3: t3 = h2@W3 ; gb = A@t3 + b3 (bf16) ----
  gemm_mfma_db<0, false, true><<<dim3(F_OUT / 128, MPAD / 128), 256, 0, stream>>>(
      h2, w3t, nullptr, t3, MPAD, H2, F_OUT);
  spmm_small<128, 0, true, true><<<cdiv(N, 16), 256, 0, stream>>>(
      row_ptr, csr_src, csr_w, t3, b3, gb, N);

  // ---- dense head (bf16 MFMA, padded widths) ----
  gemm_mfma_db<2, true, true><<<dim3(D1P / 128, MPAD / 128), 256, 0, stream>>>(
      gb, wd1t, bd1p, d1, MPAD, F_OUT, D1P);
  gemm_mfma_db<2, true, true><<<dim3(D2P / 128, MPAD / 128), 256, 0, stream>>>(
      d1, wd2t, bd2p, d2, MPAD, D1P, D2P);
  last_layer_bf16<<<cdiv(N, 256), 256, 0, stream>>>(d2, Wd3, bd3, out, N, D2, D2P);
}

// Round 8
// 286.586 us; speedup vs baseline: 1.0769x; 1.0769x over previous
//
#include <hip/hip_runtime.h>
#include <hip/hip_bf16.h>

// ---------------------------------------------------------------------------
// GCN (3x GCNConv) + dense head, bf16 MFMA.
// Round 8: v_cvt_pk_bf16_f32 epilogues (replaces 5-op manual RNE, -80% VALU
// in GEMM epilogue), single fused prep kernel (6 transposes + cvt_x +
// pad_bias + count_deg + cnt2-zero in one launch), K-loop unrolled x2 with
// compile-time LDS buffer index. GEMM pipeline structure unchanged (R7).
// ---------------------------------------------------------------------------

typedef __attribute__((ext_vector_type(8))) short bf16x8;
typedef __attribute__((ext_vector_type(8))) unsigned short u16x8;
typedef __attribute__((ext_vector_type(4))) float f32x4;
typedef unsigned short u16;

#define MPAD 20096   // 20000 padded to multiple of 128

__device__ inline u16 f2b(float f) {
  union { float f; unsigned int u; } x; x.f = f;
  unsigned int r = x.u + 0x7FFFu + ((x.u >> 16) & 1u);   // RNE
  return (u16)(r >> 16);
}
__device__ inline float b2f(u16 u) {
  union { unsigned int u; float f; } x; x.u = ((unsigned int)u) << 16; return x.f;
}
// packed f32x2 -> bf16x2 (RNE), 1 instruction (m240: no builtin on gfx950)
__device__ inline unsigned int cvt_pk_bf16(float lo, float hi) {
  unsigned int r;
  asm("v_cvt_pk_bf16_f32 %0, %1, %2" : "=v"(r) : "v"(lo), "v"(hi));
  return r;
}

// ----------------------- fused prep kernel ---------------------------------
// One launch: 5 weight transposes (fp32 [KxN] -> bf16 [NPADxKPAD], zero-fill),
// x -> bf16, bias padding, degree count, cnt2 zeroing.

__device__ inline void wT_tile(const float* __restrict__ W, u16* __restrict__ WT,
                               int K, int N, int KPAD, int NPAD,
                               int bx, int by, float (*tile)[33]) {
  const int kb = by * 32, nb = bx * 32;
  const int tx = threadIdx.x & 31, ty = threadIdx.x >> 5;
  #pragma unroll
  for (int i = 0; i < 4; ++i) {
    int k = kb + ty + i * 8, n = nb + tx;
    tile[ty + i * 8][tx] = (k < K && n < N) ? W[(size_t)k * N + n] : 0.f;
  }
  __syncthreads();
  #pragma unroll
  for (int i = 0; i < 4; ++i) {
    int n = nb + ty + i * 8, k = kb + tx;
    WT[(size_t)n * KPAD + k] = f2b(tile[tx][ty + i * 8]);
  }
}

// segments: [0,512) W1T | [512,1024) W2T | [1024,1088) W3T | [1088,1120) Wd1T
// [1120,1152) Wd2T | [1152,11152) cvt_x | 11152..3 pad_bias | [11154,12404)
// count_deg | [12404,12483) zero cnt2
__global__ __launch_bounds__(256) void prep_all(
    const float* __restrict__ x, u16* __restrict__ xb,
    const float* __restrict__ W1, u16* __restrict__ w1t,
    const float* __restrict__ W2, u16* __restrict__ w2t,
    const float* __restrict__ W3, u16* __restrict__ w3t,
    const float* __restrict__ Wd1, u16* __restrict__ wd1t,
    const float* __restrict__ Wd2, u16* __restrict__ wd2t,
    const float* __restrict__ bd1, float* __restrict__ bd1p,
    const float* __restrict__ bd2, float* __restrict__ bd2p,
    const int* __restrict__ dst, int* __restrict__ cnt1,
    int* __restrict__ cnt2) {
  __shared__ float tile[32][33];
  const int b = blockIdx.x;
  const int tid = threadIdx.x;
  if (b < 512) {
    wT_tile(W1, w1t, 512, 1024, 512, 1024, b % 32, b / 32, tile);
  } else if (b < 1024) {
    int t = b - 512;  wT_tile(W2, w2t, 1024, 512, 1024, 512, t % 16, t / 16, tile);
  } else if (b < 1088) {
    int t = b - 1024; wT_tile(W3, w3t, 512, 128, 512, 128, t % 4, t / 4, tile);
  } else if (b < 1120) {
    int t = b - 1088; wT_tile(Wd1, wd1t, 128, 152, 128, 256, t % 8, t / 8, tile);
  } else if (b < 1152) {
    int t = b - 1120; wT_tile(Wd2, wd2t, 152, 48, 256, 128, t % 4, t / 4, tile);
  } else if (b < 11152) {
    int idx = ((b - 1152) * 256 + tid) * 4;
    if (idx < 20000 * 512) {
      float4 v = *reinterpret_cast<const float4*>(&x[idx]);
      uint2 o;
      o.x = cvt_pk_bf16(v.x, v.y);
      o.y = cvt_pk_bf16(v.z, v.w);
      *reinterpret_cast<uint2*>(&xb[idx]) = o;
    }
  } else if (b == 11152) {
    bd1p[tid] = (tid < 152) ? bd1[tid] : 0.f;
  } else if (b == 11153) {
    if (tid < 128) bd2p[tid] = (tid < 48) ? bd2[tid] : 0.f;
  } else if (b < 12404) {
    int e = (b - 11154) * 256 + tid;
    if (e < 320000) atomicAdd(&cnt1[dst[e]], 1);
  } else {
    int i = (b - 12404) * 256 + tid;
    if (i < 20000) cnt2[i] = 0;
  }
}

// ----------------------- CSR scan + scatter --------------------------------

__global__ __launch_bounds__(1024) void exscan_kernel(
    const int* __restrict__ in, int* __restrict__ out, int n) {
  __shared__ int wsum[16];
  __shared__ int carry_s;
  if (threadIdx.x == 0) carry_s = 0;
  __syncthreads();
  const int lane = threadIdx.x & 63, wv = threadIdx.x >> 6;
  for (int base = 0; base < n; base += 1024) {
    int i = base + threadIdx.x;
    int v = (i < n) ? in[i] : 0;
    int s = v;
    #pragma unroll
    for (int off = 1; off < 64; off <<= 1) {
      int t = __shfl_up(s, off, 64);
      if (lane >= off) s += t;
    }
    if (lane == 63) wsum[wv] = s;
    __syncthreads();
    if (wv == 0 && lane < 16) {
      int t = wsum[lane];
      #pragma unroll
      for (int off = 1; off < 16; off <<= 1) {
        int u = __shfl_up(t, off, 64);
        if (lane >= off) t += u;
      }
      wsum[lane] = t;
    }
    __syncthreads();
    int waveoff = (wv == 0) ? 0 : wsum[wv - 1];
    int res = carry_s + waveoff + s - v;
    if (i < n) out[i] = res;
    __syncthreads();
    if (threadIdx.x == 0) carry_s += wsum[15];
    __syncthreads();
  }
  if (threadIdx.x == 0) out[n] = carry_s;
}

__global__ __launch_bounds__(256) void scatter_csr(
    const int* __restrict__ dst, const int* __restrict__ src,
    const float* __restrict__ ew, const int* __restrict__ row_ptr,
    int* __restrict__ cnt, int* __restrict__ csr_src,
    float* __restrict__ csr_w, int E) {
  int e = blockIdx.x * 256 + threadIdx.x;
  if (e >= E) return;
  int d = dst[e];
  int pos = row_ptr[d] + atomicAdd(&cnt[d], 1);
  csr_src[pos] = src[e];
  csr_w[pos] = ew[e];
}

// ----------------------- bf16 MFMA GEMM, counted-vmcnt 2-phase --------------
template <int ACT, bool BIAS, bool OUT_BF16>
__global__ __launch_bounds__(256) void gemm_mfma_db(
    const u16* __restrict__ A, const u16* __restrict__ BT,
    const float* __restrict__ bias, void* __restrict__ C,
    int M, int K, int Nn) {
  __shared__ __align__(16) u16 As[2][128 * 64];
  __shared__ __align__(16) u16 Bs[2][128 * 64];
  const int tid = threadIdx.x;
  const int lane = tid & 63;
  const int wave = tid >> 6;
  const int lo = lane & 15, hi = lane >> 4;
  const int wr = wave >> 1, wc = wave & 1;

  // bijective XCD swizzle (m204)
  const int gx = gridDim.x;
  const int nwg = gx * gridDim.y;
  const int wg = blockIdx.y * gx + blockIdx.x;
  const int q = nwg >> 3, r = nwg & 7;
  const int xcd = wg & 7, sidx = wg >> 3;
  const int swz = (xcd < r ? xcd * (q + 1) : r * (q + 1) + (xcd - r) * q) + sidx;
  const int row0 = (swz / gx) * 128;
  const int col0 = (swz % gx) * 128;

  // staging geometry: 4 chunks of 16B per thread; pre-swizzled source
  const u16* pa[4];
  const u16* pb[4];
  int so[4];
  #pragma unroll
  for (int i = 0; i < 4; ++i) {
    int o = i * 4096 + tid * 16;
    int rr = o >> 7;
    int ke = ((o & 127) >> 1) ^ ((rr & 7) << 3);
    pa[i] = &A[(size_t)(row0 + rr) * K + ke];
    pb[i] = &BT[(size_t)(col0 + rr) * K + ke];
    so[i] = o >> 1;
  }

  const int nk = K >> 6;
  f32x4 acc[4][4] = {};

  auto STAGE = [&](int buf, int kt) {
    const int ko = kt << 6;
    #pragma unroll
    for (int i = 0; i < 4; ++i) {
      __builtin_amdgcn_global_load_lds(
          (const __attribute__((address_space(1))) void*)(pa[i] + ko),
          (__attribute__((address_space(3))) void*)&As[buf][so[i]], 16, 0, 0);
      __builtin_amdgcn_global_load_lds(
          (const __attribute__((address_space(1))) void*)(pb[i] + ko),
          (__attribute__((address_space(3))) void*)&Bs[buf][so[i]], 16, 0, 0);
    }
  };

  STAGE(0, 0);
  STAGE(1, 1);
  asm volatile("s_waitcnt vmcnt(8)" ::: "memory");
  __builtin_amdgcn_s_barrier();

  auto body = [&](int cur, int kt) {   // cur is a literal at each call site
    bf16x8 af[2][4], bfr[2][4];
    #pragma unroll
    for (int ks = 0; ks < 2; ++ks) {
      #pragma unroll
      for (int m = 0; m < 4; ++m) {
        int row = wr * 64 + m * 16 + lo;
        int idx = (row * 64 + ks * 32 + hi * 8) ^ ((row & 7) << 3);
        af[ks][m] = *reinterpret_cast<const bf16x8*>(&As[cur][idx]);
      }
      #pragma unroll
      for (int n = 0; n < 4; ++n) {
        int col = wc * 64 + n * 16 + lo;
        int idx = (col * 64 + ks * 32 + hi * 8) ^ ((col & 7) << 3);
        bfr[ks][n] = *reinterpret_cast<const bf16x8*>(&Bs[cur][idx]);
      }
    }
    __builtin_amdgcn_s_setprio(1);
    #pragma unroll
    for (int ks = 0; ks < 2; ++ks)
      #pragma unroll
      for (int m = 0; m < 4; ++m)
        #pragma unroll
        for (int n = 0; n < 4; ++n)
          acc[m][n] = __builtin_amdgcn_mfma_f32_16x16x32_bf16(
              af[ks][m], bfr[ks][n], acc[m][n], 0, 0, 0);
    __builtin_amdgcn_s_setprio(0);
    asm volatile("s_waitcnt lgkmcnt(0)" ::: "memory");
    __builtin_amdgcn_s_barrier();
    if (kt + 2 < nk) {
      STAGE(cur, kt + 2);
      asm volatile("s_waitcnt vmcnt(8)" ::: "memory");
    } else if (kt + 1 < nk) {
      asm volatile("s_waitcnt vmcnt(0)" ::: "memory");
    }
    __builtin_amdgcn_s_barrier();
  };

  for (int kt = 0; kt < nk; kt += 2) {   // all nk are even (2,4,8,16)
    body(0, kt);
    body(1, kt + 1);
  }

  float bv[4];
  if (BIAS) {
    #pragma unroll
    for (int n = 0; n < 4; ++n) bv[n] = bias[col0 + wc * 64 + n * 16 + lo];
  }

  u16* Cb = (u16*)C;
  float* Cf = (float*)C;
  #pragma unroll
  for (int m = 0; m < 4; ++m) {
    int rbase = row0 + wr * 64 + m * 16 + hi * 4;
    #pragma unroll
    for (int n = 0; n < 4; ++n) {
      int c = col0 + wc * 64 + n * 16 + lo;
      float vv[4];
      #pragma unroll
      for (int i = 0; i < 4; ++i) {
        float v = acc[m][n][i];
        if (BIAS) v += bv[n];
        if (ACT == 1) v = tanhf(v);
        else if (ACT == 2) v = fmaxf(v, 0.f);
        vv[i] = v;
      }
      if (OUT_BF16) {
        unsigned int r01 = cvt_pk_bf16(vv[0], vv[1]);
        unsigned int r23 = cvt_pk_bf16(vv[2], vv[3]);
        u16* p = Cb + (size_t)rbase * Nn + c;
        p[0]            = (u16)r01;
        p[Nn]           = (u16)(r01 >> 16);
        p[2 * (size_t)Nn] = (u16)r23;
        p[3 * (size_t)Nn] = (u16)(r23 >> 16);
      } else {
        float* p = Cf + (size_t)rbase * Nn + c;
        p[0] = vv[0]; p[Nn] = vv[1];
        p[2 * (size_t)Nn] = vv[2]; p[3 * (size_t)Nn] = vv[3];
      }
    }
  }
}

// ----------------------- spmm: wave per node, F=512 -------------------------
template <int ACT, bool BIAS, bool OUT_BF16>
__global__ __launch_bounds__(256) void spmm_wave512(
    const int* __restrict__ row_ptr, const int* __restrict__ csr_src,
    const float* __restrict__ csr_w, const u16* __restrict__ H,
    const float* __restrict__ bias, void* __restrict__ out, int N) {
  __shared__ int s_src[4][64];
  __shared__ float s_w[4][64];
  const int wv = threadIdx.x >> 6;
  const int lane = threadIdx.x & 63;
  const int node = blockIdx.x * 4 + wv;
  if (node >= N) return;
  const int c = lane * 8;
  const int beg = row_ptr[node], end = row_ptr[node + 1];

  float a[8] = {};
  for (int p = beg; p < end; p += 64) {
    int cnt = end - p;
    if (cnt > 64) cnt = 64;
    if (lane < cnt) {
      s_src[wv][lane] = csr_src[p + lane];
      s_w[wv][lane] = csr_w[p + lane];
    }
    asm volatile("s_waitcnt lgkmcnt(0)" ::: "memory");
    int j = 0;
    for (; j + 3 < cnt; j += 4) {
      int s0 = s_src[wv][j], s1 = s_src[wv][j + 1];
      int s2 = s_src[wv][j + 2], s3 = s_src[wv][j + 3];
      float w0 = s_w[wv][j], w1 = s_w[wv][j + 1];
      float w2 = s_w[wv][j + 2], w3 = s_w[wv][j + 3];
      u16x8 h0 = *reinterpret_cast<const u16x8*>(&H[(size_t)s0 * 512 + c]);
      u16x8 h1 = *reinterpret_cast<const u16x8*>(&H[(size_t)s1 * 512 + c]);
      u16x8 h2 = *reinterpret_cast<const u16x8*>(&H[(size_t)s2 * 512 + c]);
      u16x8 h3 = *reinterpret_cast<const u16x8*>(&H[(size_t)s3 * 512 + c]);
      #pragma unroll
      for (int k = 0; k < 8; ++k)
        a[k] += w0 * b2f(h0[k]) + w1 * b2f(h1[k]) +
                w2 * b2f(h2[k]) + w3 * b2f(h3[k]);
    }
    for (; j < cnt; ++j) {
      int s = s_src[wv][j];
      float wt = s_w[wv][j];
      u16x8 hv = *reinterpret_cast<const u16x8*>(&H[(size_t)s * 512 + c]);
      #pragma unroll
      for (int k = 0; k < 8; ++k) a[k] += wt * b2f(hv[k]);
    }
    asm volatile("s_waitcnt lgkmcnt(0)" ::: "memory");
  }
  if (BIAS) {
    #pragma unroll
    for (int k = 0; k < 8; ++k) a[k] += bias[c + k];
  }
  if (ACT == 1) {
    #pragma unroll
    for (int k = 0; k < 8; ++k) a[k] = tanhf(a[k]);
  }
  if (OUT_BF16) {
    uint4 o;
    o.x = cvt_pk_bf16(a[0], a[1]);
    o.y = cvt_pk_bf16(a[2], a[3]);
    o.z = cvt_pk_bf16(a[4], a[5]);
    o.w = cvt_pk_bf16(a[6], a[7]);
    *reinterpret_cast<uint4*>(&((u16*)out)[(size_t)node * 512 + c]) = o;
  } else {
    float* op = &((float*)out)[(size_t)node * 512 + c];
    #pragma unroll
    for (int k = 0; k < 8; ++k) op[k] = a[k];
  }
}

// ----------------------- spmm: small F (128) --------------------------------
template <int F, int ACT, bool BIAS, bool OUT_BF16>
__global__ __launch_bounds__(256) void spmm_small(
    const int* __restrict__ row_ptr, const int* __restrict__ csr_src,
    const float* __restrict__ csr_w, const u16* __restrict__ H,
    const float* __restrict__ bias, void* __restrict__ out, int N) {
  constexpr int TPN = F / 8;
  constexpr int NPB = 256 / TPN;
  int sub = threadIdx.x / TPN;
  int ln = threadIdx.x - sub * TPN;
  int node = blockIdx.x * NPB + sub;
  if (node >= N) return;
  int c = ln * 8;
  int beg = row_ptr[node], end = row_ptr[node + 1];
  float a[8] = {};
  for (int p = beg; p < end; ++p) {
    int s = csr_src[p];
    float wt = csr_w[p];
    u16x8 hv = *reinterpret_cast<const u16x8*>(&H[(size_t)s * F + c]);
    #pragma unroll
    for (int k = 0; k < 8; ++k) a[k] += wt * b2f(hv[k]);
  }
  if (BIAS) {
    #pragma unroll
    for (int k = 0; k < 8; ++k) a[k] += bias[c + k];
  }
  if (ACT == 1) {
    #pragma unroll
    for (int k = 0; k < 8; ++k) a[k] = tanhf(a[k]);
  }
  if (OUT_BF16) {
    uint4 o;
    o.x = cvt_pk_bf16(a[0], a[1]);
    o.y = cvt_pk_bf16(a[2], a[3]);
    o.z = cvt_pk_bf16(a[4], a[5]);
    o.w = cvt_pk_bf16(a[6], a[7]);
    *reinterpret_cast<uint4*>(&((u16*)out)[(size_t)node * F + c]) = o;
  } else {
    float* op = &((float*)out)[(size_t)node * F + c];
    #pragma unroll
    for (int k = 0; k < 8; ++k) op[k] = a[k];
  }
}

// out[r] = dot(D2row(bf16)[:48], W[:48]) + b[0]
__global__ __launch_bounds__(256) void last_layer_bf16(
    const u16* __restrict__ D2v, const float* __restrict__ W,
    const float* __restrict__ b, float* __restrict__ out,
    int M, int K, int ld) {
  int rr = blockIdx.x * 256 + threadIdx.x;
  if (rr >= M) return;
  float s = b[0];
  const u16* row = &D2v[(size_t)rr * ld];
  #pragma unroll 8
  for (int k = 0; k < 48; ++k) s += b2f(row[k]) * W[k];
  out[rr] = s;
}

// ---------------------------------------------------------------------------

extern "C" void kernel_launch(void* const* d_in, const int* in_sizes, int n_in,
                              void* d_out, int out_size, void* d_ws, size_t ws_size,
                              hipStream_t stream) {
  const int N = 20000, E = 320000;
  const int F_IN = 512, H1 = 1024, H2 = 512, F_OUT = 128;
  const int D1P = 256, D2P = 128;

  const float* x    = (const float*)d_in[0];
  const int*   src  = (const int*)d_in[1];
  const int*   dst  = (const int*)d_in[2];
  const float* ew   = (const float*)d_in[3];
  const float* W1   = (const float*)d_in[4];
  const float* b1   = (const float*)d_in[5];
  const float* W2   = (const float*)d_in[6];
  const float* b2   = (const float*)d_in[7];
  const float* W3   = (const float*)d_in[8];
  const float* b3   = (const float*)d_in[9];
  const float* Wd1  = (const float*)d_in[10];
  const float* bd1  = (const float*)d_in[11];
  const float* Wd2  = (const float*)d_in[12];
  const float* bd2  = (const float*)d_in[13];
  const float* Wd3  = (const float*)d_in[14];
  const float* bd3  = (const float*)d_in[15];
  float* out = (float*)d_out;

  size_t off = 0;
  auto alloc = [&](size_t bytes) {
    void* p = (char*)d_ws + off;
    off += (bytes + 255) & ~(size_t)255;
    return p;
  };
  u16* xb   = (u16*)alloc((size_t)MPAD * F_IN * 2);    // x bf16; later t2
  u16* ax   = (u16*)alloc((size_t)MPAD * F_IN * 2);    // A@x;   later h2
  u16* h1   = (u16*)alloc((size_t)MPAD * H1 * 2);      // h1 (also t3..d2 region)
  u16* w1t  = (u16*)alloc((size_t)H1 * F_IN * 2);
  u16* w2t  = (u16*)alloc((size_t)H2 * H1 * 2);
  u16* w3t  = (u16*)alloc((size_t)F_OUT * H2 * 2);
  u16* wd1t = (u16*)alloc((size_t)D1P * F_OUT * 2);
  u16* wd2t = (u16*)alloc((size_t)D2P * D1P * 2);
  float* bd1p = (float*)alloc((size_t)D1P * 4);
  float* bd2p = (float*)alloc((size_t)D2P * 4);
  int* row_ptr = (int*)alloc((size_t)(N + 1) * 4);
  int* cnt1    = (int*)alloc((size_t)N * 4);
  int* cnt2    = (int*)alloc((size_t)N * 4);
  int* csr_src = (int*)alloc((size_t)E * 4);
  float* csr_w = (float*)alloc((size_t)E * 4);

  u16* t2 = xb;
  u16* h2 = ax;
  u16* t3 = h1;
  u16* gb = t3 + (size_t)MPAD * F_OUT;
  u16* d1 = gb + (size_t)MPAD * F_OUT;
  u16* d2 = d1 + (size_t)MPAD * D1P;

  auto cdiv = [](int a, int b) { return (a + b - 1) / b; };

  // ---- prep: zero cnt1, then one fused kernel for all conversions + count ----
  hipMemsetAsync(cnt1, 0, (size_t)N * 4, stream);
  prep_all<<<12483, 256, 0, stream>>>(x, xb, W1, w1t, W2, w2t, W3, w3t,
                                      Wd1, wd1t, Wd2, wd2t, bd1, bd1p,
                                      bd2, bd2p, dst, cnt1, cnt2);
  exscan_kernel<<<1, 1024, 0, stream>>>(cnt1, row_ptr, N);
  scatter_csr<<<cdiv(E, 256), 256, 0, stream>>>(dst, src, ew, row_ptr, cnt2,
                                                csr_src, csr_w, E);

  // ---- layer 1 (reordered): ax = A@x ; h1 = tanh(ax@W1 + b1) ----
  spmm_wave512<0, false, true><<<cdiv(N, 4), 256, 0, stream>>>(
      row_ptr, csr_src, csr_w, xb, nullptr, ax, N);
  gemm_mfma_db<1, true, true><<<dim3(H1 / 128, MPAD / 128), 256, 0, stream>>>(
      ax, w1t, b1, h1, MPAD, F_IN, H1);

  // ---- layer 2: t2 = h1@W2 ; h2 = tanh(A@t2 + b2) ----
  gemm_mfma_db<0, false, true><<<dim3(H2 / 128, MPAD / 128), 256, 0, stream>>>(
      h1, w2t, nullptr, t2, MPAD, H1, H2);
  spmm_wave512<1, true, true><<<cdiv(N, 4), 256, 0, stream>>>(
      row_ptr, csr_src, csr_w, t2, b2, h2, N);

  // ---- layer 3: t3 = h2@W3 ; gb = A@t3 + b3 (bf16) ----
  gemm_mfma_db<0, false, true><<<dim3(F_OUT / 128, MPAD / 128), 256, 0, stream>>>(
      h2, w3t, nullptr, t3, MPAD, H2, F_OUT);
  spmm_small<128, 0, true, true><<<cdiv(N, 16), 256, 0, stream>>>(
      row_ptr, csr_src, csr_w, t3, b3, gb, N);

  // ---- dense head (bf16 MFMA, padded widths) ----
  gemm_mfma_db<2, true, true><<<dim3(D1P / 128, MPAD / 128), 256, 0, stream>>>(
      gb, wd1t, bd1p, d1, MPAD, F_OUT, D1P);
  gemm_mfma_db<2, true, true><<<dim3(D2P / 128, MPAD / 128), 256, 0, stream>>>(
      d1, wd2t, bd2p, d2, MPAD, D1P, D2P);
  last_layer_bf16<<<cdiv(N, 256), 256, 0, stream>>>(d2, Wd3, bd3, out, N, 48, D2P);
}